// Round 6
// baseline (1286.221 us; speedup 1.0000x reference)
//
#include <hip/hip_runtime.h>
#include <math.h>

#define B_ 4
#define L_ 2048
#define D_ 1024
#define H_ 16
#define HD_ 64
#define K_ 24
#define MLP_ 4096

typedef unsigned short u16;
typedef short s16x8 __attribute__((ext_vector_type(8)));
typedef float fx4 __attribute__((ext_vector_type(4)));

__device__ __forceinline__ u16 f2bf(float f) {
    unsigned u = __float_as_uint(f);
    unsigned r = (u + 0x7fff + ((u >> 16) & 1)) >> 16;
    return (u16)r;
}

__device__ __forceinline__ float gelu_t(float x) {
    float u = 0.7978845608028654f * (x + 0.044715f * x * x * x);
    return x / (1.f + __expf(-2.f * u));
}

__device__ __forceinline__ void gload_lds16(const void* g, void* l) {
    __builtin_amdgcn_global_load_lds(
        (const __attribute__((address_space(1))) unsigned int*)g,
        (__attribute__((address_space(3))) unsigned int*)l, 16, 0, 0);
}

// ---------------------------------------------------------------------------
// filters[l,d] = sum_k eig_vecs[l,k] * eig_vals[k]^0.25 * w_filters[k,d]
// ---------------------------------------------------------------------------
__global__ void filters_kernel(const float* __restrict__ eig_vals,
                               const float* __restrict__ eig_vecs,
                               const float* __restrict__ w_filters,
                               float* __restrict__ out) {
    int l = blockIdx.x;
    int d = blockIdx.y * 256 + threadIdx.x;
    __shared__ float r[K_];
    if (threadIdx.x < K_) {
        float ev = eig_vals[threadIdx.x];
        r[threadIdx.x] = eig_vecs[l * K_ + threadIdx.x] * powf(ev, 0.25f);
    }
    __syncthreads();
    float acc = 0.f;
#pragma unroll
    for (int k = 0; k < K_; k++) acc += r[k] * w_filters[k * D_ + d];
    out[(size_t)l * D_ + d] = acc;
}

// ---------------------------------------------------------------------------
__global__ __launch_bounds__(256) void cast_bf16(const float* __restrict__ in,
                                                 u16* __restrict__ out) {
    int i = blockIdx.x * 256 + threadIdx.x;
    float4 v = ((const float4*)in)[i];
    ushort4 o;
    o.x = f2bf(v.x); o.y = f2bf(v.y); o.z = f2bf(v.z); o.w = f2bf(v.w);
    ((ushort4*)out)[i] = o;
}

// ---------------------------------------------------------------------------
// fp32 [R][C] -> bf16 [C][R] transpose-cast (32x32 LDS tile)
// ---------------------------------------------------------------------------
__global__ __launch_bounds__(256) void cast_T(const float* __restrict__ in,
                                              u16* __restrict__ out, int R, int C) {
    __shared__ float t[32][33];
    int c0 = blockIdx.x * 32, r0 = blockIdx.y * 32;
    int tx = threadIdx.x & 31, ty = threadIdx.x >> 5;
#pragma unroll
    for (int p = 0; p < 4; p++)
        t[ty + p * 8][tx] = in[(size_t)(r0 + ty + p * 8) * C + c0 + tx];
    __syncthreads();
#pragma unroll
    for (int p = 0; p < 4; p++)
        out[(size_t)(c0 + ty + p * 8) * R + r0 + tx] = f2bf(t[tx][ty + p * 8]);
}

// 3 same-shape DxD transposes in one launch (wq/wk/wv -> fused QKV weights)
__global__ __launch_bounds__(256) void cast_T_qkv(const float* __restrict__ wq,
                                                  const float* __restrict__ wk,
                                                  const float* __restrict__ wv,
                                                  u16* __restrict__ out) {
    const float* in = blockIdx.z == 0 ? wq : (blockIdx.z == 1 ? wk : wv);
    u16* o = out + (size_t)blockIdx.z * D_ * D_;
    __shared__ float t[32][33];
    int c0 = blockIdx.x * 32, r0 = blockIdx.y * 32;
    int tx = threadIdx.x & 31, ty = threadIdx.x >> 5;
#pragma unroll
    for (int p = 0; p < 4; p++)
        t[ty + p * 8][tx] = in[(size_t)(r0 + ty + p * 8) * D_ + c0 + tx];
    __syncthreads();
#pragma unroll
    for (int p = 0; p < 4; p++)
        o[(size_t)(c0 + ty + p * 8) * D_ + r0 + tx] = f2bf(t[tx][ty + p * 8]);
}

// ---------------------------------------------------------------------------
// bf16 MFMA GEMM: out = act(alpha * A @ Bt^T + bias) + resid
// qcols: columns < qcols get alpha*0.125 (fused-QKV Q-scale)
// ---------------------------------------------------------------------------
__global__ __launch_bounds__(256) void gemm_bf16(
    const u16* __restrict__ A, const u16* __restrict__ Bt,
    float* __restrict__ C, u16* __restrict__ Cb,
    int M, int N, int K, float alpha,
    const float* __restrict__ bias, const float* __restrict__ resid, int act,
    int qcols) {
    __shared__ u16 As[4][128][8];
    __shared__ u16 Bs[4][128][8];
    int tid = threadIdx.x;
    int wid = tid >> 6, lane = tid & 63;
    int bm = blockIdx.y * 128, bn = blockIdx.x * 128;
    int wm = (wid >> 1) * 64, wn = (wid & 1) * 64;
    int q = lane >> 4, r = lane & 15;

    const u16* gA0 = A + (size_t)(bm + lane) * K + wid * 8;
    const u16* gA1 = gA0 + (size_t)64 * K;
    const u16* gB0 = Bt + (size_t)(bn + lane) * K + wid * 8;
    const u16* gB1 = gB0 + (size_t)64 * K;
    u16* lA0 = &As[wid][0][0];
    u16* lA1 = &As[wid][64][0];
    u16* lB0 = &Bs[wid][0][0];
    u16* lB1 = &Bs[wid][64][0];
    const u16* pa = &As[q][wm + r][0];
    const u16* pb = &Bs[q][wn + r][0];

    fx4 acc[4][4];
#pragma unroll
    for (int i = 0; i < 4; i++)
#pragma unroll
        for (int j = 0; j < 4; j++) acc[i][j] = (fx4){0.f, 0.f, 0.f, 0.f};

    for (int k0 = 0; k0 < K; k0 += 32) {
        if (k0) __syncthreads();
        gload_lds16(gA0 + k0, lA0);
        gload_lds16(gA1 + k0, lA1);
        gload_lds16(gB0 + k0, lB0);
        gload_lds16(gB1 + k0, lB1);
        __syncthreads();
        s16x8 a[4], b[4];
#pragma unroll
        for (int i = 0; i < 4; i++) a[i] = *(const s16x8*)(pa + i * 128);
#pragma unroll
        for (int j = 0; j < 4; j++) b[j] = *(const s16x8*)(pb + j * 128);
#pragma unroll
        for (int i = 0; i < 4; i++)
#pragma unroll
            for (int j = 0; j < 4; j++)
                acc[i][j] = __builtin_amdgcn_mfma_f32_16x16x32_bf16(
                    a[i], b[j], acc[i][j], 0, 0, 0);
    }

#pragma unroll
    for (int i = 0; i < 4; i++) {
        int row0 = bm + wm + i * 16 + q * 4;
#pragma unroll
        for (int j = 0; j < 4; j++) {
            int col = bn + wn + j * 16 + r;
            float a2 = (col < qcols) ? alpha * 0.125f : alpha;
            float bv = bias ? bias[col] : 0.f;
#pragma unroll
            for (int reg = 0; reg < 4; reg++) {
                float v = a2 * acc[i][j][reg] + bv;
                if (act) v = gelu_t(v);
                size_t idx = (size_t)(row0 + reg) * N + col;
                if (resid) v += resid[idx];
                if (C) C[idx] = v;
                else Cb[idx] = f2bf(v);
            }
        }
    }
}

// ---------------------------------------------------------------------------
// Causal per-channel conv: out[b,l,d] = sum_{t=0..l} F[t,d]*XI[b,l-t,d]
// v3: 128-l tiles, paired (i, 15-i) -> every block exactly 34 iterations.
// Per iteration: 2048 thread-FMAs per 64KB staged (2x round-5 density).
// Layouts (stride%8==4 -> wave64 b128 hits uniform 8-access/bank minimum):
//   xs[d][c] stride 196, c in [0,192) = j in [jb, jb+191], jb=l0-t0-63
//   ft[d][t] stride 68 (transposed filter tile)
// Thread (dd=tid&63, jg=tid>>6) computes l = l0 + jg*32 + i, i in [0,32).
// 40-register ring window W, all indices compile-time (c' = c - L0).
// ---------------------------------------------------------------------------
__global__ __launch_bounds__(256) void conv_k(const float* __restrict__ F,
                                              const float* __restrict__ XI,
                                              float* __restrict__ OUT) {
    int d0 = blockIdx.y * 64, b = blockIdx.z;
    __shared__ float xs[64][196];
    __shared__ float ft[64][68];
    int tid = threadIdx.x;
    int dd = tid & 63;
    int jg = tid >> 6;
    int L0 = jg * 32;
    const float* xib = XI + (size_t)b * L_ * D_;

#pragma unroll 1
    for (int half = 0; half < 2; half++) {
        int lt = half ? (15 - blockIdx.x) : blockIdx.x;
        int l0 = lt * 128;
        float acc[32];
#pragma unroll
        for (int i = 0; i < 32; i++) acc[i] = 0.f;

        for (int t0 = 0; t0 <= l0 + 64; t0 += 64) {
            int jb = l0 - t0 - 63;
            // stage filters transposed: ft[d][t]
#pragma unroll
            for (int mm = 0; mm < 4; mm++) {
                int t4 = (jg + 4 * mm) * 4;
                float4 v;
                v.x = F[(size_t)(t0 + t4 + 0) * D_ + d0 + dd];
                v.y = F[(size_t)(t0 + t4 + 1) * D_ + d0 + dd];
                v.z = F[(size_t)(t0 + t4 + 2) * D_ + d0 + dd];
                v.w = F[(size_t)(t0 + t4 + 3) * D_ + d0 + dd];
                *(float4*)&ft[dd][t4] = v;
            }
            // stage xi window: xs[d][c] = XI[jb+c, d], zero outside [0,L)
            if (jb >= 0 && jb + 191 < L_) {
#pragma unroll
                for (int mm = 0; mm < 12; mm++) {
                    int c0 = jg * 48 + mm * 4;
                    float4 v;
                    v.x = xib[(size_t)(jb + c0 + 0) * D_ + d0 + dd];
                    v.y = xib[(size_t)(jb + c0 + 1) * D_ + d0 + dd];
                    v.z = xib[(size_t)(jb + c0 + 2) * D_ + d0 + dd];
                    v.w = xib[(size_t)(jb + c0 + 3) * D_ + d0 + dd];
                    *(float4*)&xs[dd][c0] = v;
                }
            } else {
#pragma unroll
                for (int mm = 0; mm < 12; mm++) {
                    int c0 = jg * 48 + mm * 4;
                    float4 v;
#pragma unroll
                    for (int k = 0; k < 4; k++) {
                        int j = jb + c0 + k;
                        ((float*)&v)[k] = (j >= 0 && j < L_)
                            ? xib[(size_t)j * D_ + d0 + dd] : 0.f;
                    }
                    *(float4*)&xs[dd][c0] = v;
                }
            }
            __syncthreads();

            // init ring: c' = 60..95  (c' = physical col - L0)
            float W[40];
#pragma unroll
            for (int mm = 0; mm < 9; mm++) {
                float4 v = *(const float4*)&xs[dd][L0 + 60 + 4 * mm];
                W[(60 + 4 * mm) % 40] = v.x;
                W[(61 + 4 * mm) % 40] = v.y;
                W[(62 + 4 * mm) % 40] = v.z;
                W[(63 + 4 * mm) % 40] = v.w;
            }
#pragma unroll
            for (int s = 0; s < 16; s++) {
                float4 f4 = *(const float4*)&ft[dd][4 * s];
                float4 nx;
                if (s < 15) nx = *(const float4*)&xs[dd][L0 + 56 - 4 * s];
                // acc[i] += f(tau=4s+k) * x[c' = i + 63 - 4s - k]
#pragma unroll
                for (int i = 0; i < 32; i++) acc[i] += f4.x * W[(i + 63 - 4 * s) % 40];
#pragma unroll
                for (int i = 0; i < 32; i++) acc[i] += f4.y * W[(i + 62 - 4 * s) % 40];
#pragma unroll
                for (int i = 0; i < 32; i++) acc[i] += f4.z * W[(i + 61 - 4 * s) % 40];
#pragma unroll
                for (int i = 0; i < 32; i++) acc[i] += f4.w * W[(i + 60 - 4 * s) % 40];
                if (s < 15) {
                    W[(56 - 4 * s + 40) % 40] = nx.x;
                    W[(57 - 4 * s + 40) % 40] = nx.y;
                    W[(58 - 4 * s + 40) % 40] = nx.z;
                    W[(59 - 4 * s + 40) % 40] = nx.w;
                }
            }
            __syncthreads();
        }
#pragma unroll
        for (int i = 0; i < 32; i++)
            OUT[((size_t)b * L_ + l0 + L0 + i) * D_ + d0 + dd] = acc[i];
    }
}

// ---------------------------------------------------------------------------
// LayerNorm -> bf16 out (row = 1024), eps 1e-6
// ---------------------------------------------------------------------------
__global__ __launch_bounds__(256) void layernorm_bf16(const float* __restrict__ x,
                                                      const float* __restrict__ scale,
                                                      const float* __restrict__ bias,
                                                      u16* __restrict__ y) {
    size_t row = blockIdx.x;
    int tid = threadIdx.x;
    const float4 v = *(const float4*)&x[row * D_ + tid * 4];
    float s = v.x + v.y + v.z + v.w;
    float q = v.x * v.x + v.y * v.y + v.z * v.z + v.w * v.w;
#pragma unroll
    for (int off = 32; off >= 1; off >>= 1) {
        s += __shfl_xor(s, off, 64);
        q += __shfl_xor(q, off, 64);
    }
    __shared__ float ss[4], sq[4];
    int w = tid >> 6;
    if ((tid & 63) == 0) { ss[w] = s; sq[w] = q; }
    __syncthreads();
    s = ss[0] + ss[1] + ss[2] + ss[3];
    q = sq[0] + sq[1] + sq[2] + sq[3];
    float mean = s * (1.f / D_);
    float var = q * (1.f / D_) - mean * mean;
    float r = rsqrtf(var + 1e-6f);
    const float4 sc = *(const float4*)&scale[tid * 4];
    const float4 bi = *(const float4*)&bias[tid * 4];
    ushort4 o;
    o.x = f2bf((v.x - mean) * r * sc.x + bi.x);
    o.y = f2bf((v.y - mean) * r * sc.y + bi.y);
    o.z = f2bf((v.z - mean) * r * sc.z + bi.z);
    o.w = f2bf((v.w - mean) * r * sc.w + bi.w);
    *(ushort4*)&y[row * D_ + tid * 4] = o;
}

// ---------------------------------------------------------------------------
// MFMA flash attention, TQ=128. Q,K,V are column slices of the fused
// [B*L, 3072] bf16 QKV buffer (stride 3072); Q pre-scaled. Out bf16 [M,1024].
// ps overlays qs (aq hoisted to regs; each wave only touches its own rows).
// ---------------------------------------------------------------------------
__global__ __launch_bounds__(256) void attn_mfma(const u16* __restrict__ Qg,
                                                 const u16* __restrict__ Kg,
                                                 const u16* __restrict__ Vg,
                                                 u16* __restrict__ Og) {
    const int QSTR = 3072;
    int q0 = blockIdx.x * 128;
    int b = blockIdx.y >> 4, h = blockIdx.y & 15;
    __shared__ __align__(16) u16 qs[128 * 72];
    __shared__ __align__(16) u16 ks[64 * 72];
    __shared__ __align__(16) u16 vt[64 * 72];   // V^T: [hd][s]
    int tid = threadIdx.x;
    int w = tid >> 6, lane = tid & 63;
    int quad = lane >> 4, l15 = lane & 15;
    const size_t base = (size_t)b * L_ * QSTR + h * HD_;

#pragma unroll
    for (int i = tid; i < 128 * 8; i += 256) {
        int r = i >> 3, c = i & 7;
        *(uint4*)&qs[r * 72 + c * 8] =
            *(const uint4*)&Qg[base + (size_t)(q0 + r) * QSTR + c * 8];
    }
    __syncthreads();
    s16x8 aq[2][2];
#pragma unroll
    for (int mi = 0; mi < 2; mi++)
#pragma unroll
        for (int kb = 0; kb < 2; kb++)
            aq[mi][kb] = *(const s16x8*)&qs[(w * 32 + mi * 16 + l15) * 72 + kb * 32 + quad * 8];

    float m[2][4], lsum[2][4];
    fx4 o[2][4];
#pragma unroll
    for (int mi = 0; mi < 2; mi++)
#pragma unroll
        for (int i = 0; i < 4; i++) {
            m[mi][i] = -1e30f; lsum[mi][i] = 0.f;
            o[mi][i] = (fx4){0.f, 0.f, 0.f, 0.f};
        }
    u16* psw = qs + w * 32 * 72;   // wave-private (rows this wave hoisted)

    for (int s0 = 0; s0 < L_; s0 += 64) {
        __syncthreads();
#pragma unroll
        for (int i = tid; i < 64 * 8; i += 256) {
            int r = i >> 3, c = i & 7;
            *(uint4*)&ks[r * 72 + c * 8] =
                *(const uint4*)&Kg[base + (size_t)(s0 + r) * QSTR + c * 8];
        }
        {
            int s = lane;
#pragma unroll
            for (int it = 0; it < 2; it++) {
                int hd0 = w * 8 + it * 32;
                uint4 v = *(const uint4*)&Vg[base + (size_t)(s0 + s) * QSTR + hd0];
                u16 tmp[8];
                *(uint4*)tmp = v;
#pragma unroll
                for (int j = 0; j < 8; j++) vt[(hd0 + j) * 72 + s] = tmp[j];
            }
        }
        __syncthreads();

        fx4 sv[2][4];
#pragma unroll
        for (int mi = 0; mi < 2; mi++)
#pragma unroll
            for (int nt = 0; nt < 4; nt++) sv[mi][nt] = (fx4){0.f, 0.f, 0.f, 0.f};
#pragma unroll
        for (int kb = 0; kb < 2; kb++)
#pragma unroll
            for (int nt = 0; nt < 4; nt++) {
                s16x8 bk = *(const s16x8*)&ks[(nt * 16 + l15) * 72 + kb * 32 + quad * 8];
#pragma unroll
                for (int mi = 0; mi < 2; mi++)
                    sv[mi][nt] = __builtin_amdgcn_mfma_f32_16x16x32_bf16(
                        aq[mi][kb], bk, sv[mi][nt], 0, 0, 0);
            }

#pragma unroll
        for (int mi = 0; mi < 2; mi++) {
            float mx[4], cor[4], rs[4];
#pragma unroll
            for (int reg = 0; reg < 4; reg++)
                mx[reg] = fmaxf(fmaxf(sv[mi][0][reg], sv[mi][1][reg]),
                                fmaxf(sv[mi][2][reg], sv[mi][3][reg]));
#pragma unroll
            for (int off = 8; off >= 1; off >>= 1)
#pragma unroll
                for (int reg = 0; reg < 4; reg++)
                    mx[reg] = fmaxf(mx[reg], __shfl_xor(mx[reg], off, 16));
#pragma unroll
            for (int reg = 0; reg < 4; reg++) {
                float mn = fmaxf(m[mi][reg], mx[reg]);
                cor[reg] = __expf(m[mi][reg] - mn);
                m[mi][reg] = mn;
                rs[reg] = 0.f;
            }
#pragma unroll
            for (int nt = 0; nt < 4; nt++)
#pragma unroll
                for (int reg = 0; reg < 4; reg++) {
                    float p = __expf(sv[mi][nt][reg] - m[mi][reg]);
                    sv[mi][nt][reg] = p;
                    rs[reg] += p;
                }
#pragma unroll
            for (int off = 8; off >= 1; off >>= 1)
#pragma unroll
                for (int reg = 0; reg < 4; reg++)
                    rs[reg] += __shfl_xor(rs[reg], off, 16);
#pragma unroll
            for (int reg = 0; reg < 4; reg++)
                lsum[mi][reg] = lsum[mi][reg] * cor[reg] + rs[reg];
#pragma unroll
            for (int nt = 0; nt < 4; nt++) {
                fx4 on = o[mi][nt];
                on[0] *= cor[0]; on[1] *= cor[1]; on[2] *= cor[2]; on[3] *= cor[3];
                o[mi][nt] = on;
            }
#pragma unroll
            for (int nt = 0; nt < 4; nt++)
#pragma unroll
                for (int reg = 0; reg < 4; reg++)
                    psw[(mi * 16 + quad * 4 + reg) * 72 + nt * 16 + l15] =
                        f2bf(sv[mi][nt][reg]);
        }
#pragma unroll
        for (int kb = 0; kb < 2; kb++) {
            s16x8 ap[2];
#pragma unroll
            for (int mi = 0; mi < 2; mi++)
                ap[mi] = *(const s16x8*)&psw[(mi * 16 + l15) * 72 + kb * 32 + quad * 8];
#pragma unroll
            for (int nt = 0; nt < 4; nt++) {
                s16x8 bv = *(const s16x8*)&vt[(nt * 16 + l15) * 72 + kb * 32 + quad * 8];
#pragma unroll
                for (int mi = 0; mi < 2; mi++)
                    o[mi][nt] = __builtin_amdgcn_mfma_f32_16x16x32_bf16(
                        ap[mi], bv, o[mi][nt], 0, 0, 0);
            }
        }
    }
    const size_t baseo = (size_t)b * L_ * 1024 + h * HD_;
#pragma unroll
    for (int mi = 0; mi < 2; mi++)
#pragma unroll
        for (int reg = 0; reg < 4; reg++) {
            float inv = 1.f / lsum[mi][reg];
            size_t row = baseo +
                (size_t)(q0 + w * 32 + mi * 16 + quad * 4 + reg) * 1024;
#pragma unroll
            for (int nt = 0; nt < 4; nt++)
                Og[row + nt * 16 + l15] = f2bf(o[mi][nt][reg] * inv);
        }
}

// ---------------------------------------------------------------------------
extern "C" void kernel_launch(void* const* d_in, const int* in_sizes, int n_in,
                              void* d_out, int out_size, void* d_ws, size_t ws_size,
                              hipStream_t stream) {
    const float* inputs   = (const float*)d_in[0];
    const float* eig_vals = (const float*)d_in[1];
    const float* eig_vecs = (const float*)d_in[2];
    const float* w_filt   = (const float*)d_in[3];
    const float* w_inp    = (const float*)d_in[4];
    const float* ln1_s    = (const float*)d_in[5];
    const float* ln1_b    = (const float*)d_in[6];
    const float* wq       = (const float*)d_in[7];
    const float* wk       = (const float*)d_in[8];
    const float* wv       = (const float*)d_in[9];
    const float* wo       = (const float*)d_in[10];
    const float* ln2_s    = (const float*)d_in[11];
    const float* ln2_b    = (const float*)d_in[12];
    const float* w1       = (const float*)d_in[13];
    const float* b1       = (const float*)d_in[14];
    const float* w2       = (const float*)d_in[15];
    const float* b2       = (const float*)d_in[16];
    float* out = (float*)d_out;
    char* ws = (char*)d_ws;
    const size_t MB = 1u << 20;
    u16*   INb   = (u16*)(ws + 0 * MB);
    u16*   WIt   = (u16*)(ws + 16 * MB);
    u16*   WQKVt = (u16*)(ws + 18 * MB);
    u16*   WOt   = (u16*)(ws + 24 * MB);
    u16*   W1t   = (u16*)(ws + 26 * MB);
    u16*   W2t   = (u16*)(ws + 34 * MB);
    float* XI    = (float*)(ws + 48 * MB);
    u16*   HID   = (u16*)(ws + 48 * MB);
    float* STU   = (float*)(ws + 80 * MB);
    u16*   XN    = (u16*)(ws + 112 * MB);
    u16*   QKV   = (u16*)(ws + 128 * MB);
    float* Xb    = (float*)(ws + 128 * MB);
    u16*   YN    = (u16*)(ws + 160 * MB);
    float* Fv    = (float*)(ws + 176 * MB);
    u16*   Ab    = (u16*)(ws + 176 * MB);

    const int M = B_ * L_;

    cast_bf16<<<(M * D_ / 4 + 255) / 256, 256, 0, stream>>>(inputs, INb);
    cast_T<<<dim3(D_ / 32, D_ / 32), 256, 0, stream>>>(w_inp, WIt, D_, D_);
    cast_T_qkv<<<dim3(D_ / 32, D_ / 32, 3), 256, 0, stream>>>(wq, wk, wv, WQKVt);
    cast_T<<<dim3(D_ / 32, D_ / 32), 256, 0, stream>>>(wo, WOt, D_, D_);
    cast_T<<<dim3(MLP_ / 32, D_ / 32), 256, 0, stream>>>(w1, W1t, D_, MLP_);
    cast_T<<<dim3(D_ / 32, MLP_ / 32), 256, 0, stream>>>(w2, W2t, MLP_, D_);

    filters_kernel<<<dim3(L_, D_ / 256), 256, 0, stream>>>(eig_vals, eig_vecs, w_filt, Fv);

    gemm_bf16<<<dim3(D_ / 128, M / 128), 256, 0, stream>>>(
        INb, WIt, XI, nullptr, M, D_, D_, 1.f, nullptr, nullptr, 0, 0);
    conv_k<<<dim3(8, D_ / 64, B_), 256, 0, stream>>>(Fv, XI, STU);
    layernorm_bf16<<<M, 256, 0, stream>>>(STU, ln1_s, ln1_b, XN);
    gemm_bf16<<<dim3(3 * D_ / 128, M / 128), 256, 0, stream>>>(
        XN, WQKVt, nullptr, QKV, M, 3 * D_, D_, 1.f, nullptr, nullptr, 0, D_);
    attn_mfma<<<dim3(L_ / 128, B_ * H_), 256, 0, stream>>>(
        QKV, QKV + D_, QKV + 2 * D_, Ab);
    gemm_bf16<<<dim3(D_ / 128, M / 128), 256, 0, stream>>>(
        Ab, WOt, Xb, nullptr, M, D_, D_, 1.f, nullptr, STU, 0, 0);
    layernorm_bf16<<<M, 256, 0, stream>>>(Xb, ln2_s, ln2_b, YN);
    gemm_bf16<<<dim3(MLP_ / 128, M / 128), 256, 0, stream>>>(
        YN, W1t, nullptr, HID, M, MLP_, D_, 1.f, b1, nullptr, 1, 0);
    gemm_bf16<<<dim3(D_ / 128, M / 128), 256, 0, stream>>>(
        HID, W2t, out, nullptr, M, D_, MLP_, 1.f, b2, Xb, 0, 0);
}